// Round 3
// baseline (1218.523 us; speedup 1.0000x reference)
//
#include <hip/hip_runtime.h>

#define NBATCH   16384
#define TSTEPS   50
#define HDIM     64
#define HOR      50
#define NB       32   // batches per block
#define NW       8    // batches per wave
#define NTHREADS 256

__device__ __forceinline__ float frcp(float x) { return __builtin_amdgcn_rcpf(x); }
__device__ __forceinline__ float sigmoidf(float x) { return frcp(1.f + __expf(-x)); }
__device__ __forceinline__ float tanh_fast(float x) {
  float ax = fabsf(x);
  float e  = __expf(-2.f * ax);
  float r  = (1.f - e) * frcp(1.f + e);
  return copysignf(r, x);
}
__device__ __forceinline__ float readlane_f(float v, int lane) {
  return __int_as_float(__builtin_amdgcn_readlane(__float_as_int(v), lane));
}

__global__ __launch_bounds__(NTHREADS, 2)
void traj_lstm_kernel(const float* __restrict__ hist,   // (B, 50, 2)
                      const float* __restrict__ W_ih,   // (256, 2)
                      const float* __restrict__ W_hh,   // (256, 64)
                      const float* __restrict__ b_ih,   // (256)
                      const float* __restrict__ b_hh,   // (256)
                      const float* __restrict__ W_dec,  // (2, 64)
                      const float* __restrict__ b_dec,  // (2)
                      float* __restrict__ out)          // (B, 50, 2)
{
  // Wq[k][j] = { W_hh[j][k], W_hh[j+64][k], W_hh[j+128][k], W_hh[j+192][k] }
  __shared__ float4 Wq[HDIM][HDIM];     // 64 KB
  __shared__ float hbuf[NB][HDIM + 4];  // decoder-only h exchange
  __shared__ float Wd[2][HDIM];
  __shared__ float xdec[NB][2];

  const int t  = threadIdx.x;
  const int j  = t & 63;    // hidden index owned by this lane
  const int w  = t >> 6;    // wave id (0..3)
  const int lb = w * NW;    // local batch base
  const int gb = blockIdx.x * NB + lb;

  // ---- one-time staging (stride-16B lane writes => conflict-free) ----
  for (int idx = t; idx < HDIM * HDIM; idx += NTHREADS) {
    const int jj = idx & 63;
    const int kk = idx >> 6;
    float4 wv;
    wv.x = W_hh[(jj      ) * HDIM + kk];
    wv.y = W_hh[(jj +  64) * HDIM + kk];
    wv.z = W_hh[(jj + 128) * HDIM + kk];
    wv.w = W_hh[(jj + 192) * HDIM + kk];
    Wq[kk][jj] = wv;
  }
  if (t < 2 * HDIM) Wd[t >> 6][t & 63] = W_dec[t];

  float biasr[4], wi0[4], wi1[4];
  #pragma unroll
  for (int g = 0; g < 4; ++g) {
    int r = j + 64 * g;
    biasr[g] = b_ih[r] + b_hh[r];
    wi0[g]   = W_ih[2 * r];
    wi1[g]   = W_ih[2 * r + 1];
  }
  const float bd0 = b_dec[0], bd1 = b_dec[1];

  float c[NW], h_reg[NW];
  #pragma unroll
  for (int bb = 0; bb < NW; ++bb) { c[bb] = 0.f; h_reg[bb] = 0.f; }
  __syncthreads();  // Wq/Wd visible; loop below is barrier-free (wave-local)

  const float2* __restrict__ histv = (const float2*)hist;

  for (int s = 0; s < TSTEPS + HOR; ++s) {
    // ---- input x for this step ----
    float x0[NW], x1[NW];
    if (s <= TSTEPS) {
      const int ss = (s < TSTEPS) ? s : (TSTEPS - 1);
      #pragma unroll
      for (int bb = 0; bb < NW; ++bb) {
        float2 xv = histv[(size_t)(gb + bb) * TSTEPS + ss];
        x0[bb] = xv.x; x1[bb] = xv.y;
      }
    } else {
      #pragma unroll
      for (int bb = 0; bb < NW; ++bb) {
        x0[bb] = xdec[lb + bb][0];
        x1[bb] = xdec[lb + bb][1];
      }
    }

    // ---- gates = h @ W_hh.T : Wq from LDS, h broadcast via v_readlane ----
    float acc[NW][4];
    #pragma unroll
    for (int bb = 0; bb < NW; ++bb) {
      acc[bb][0] = 0.f; acc[bb][1] = 0.f; acc[bb][2] = 0.f; acc[bb][3] = 0.f;
    }

    #pragma unroll 4
    for (int k = 0; k < HDIM; ++k) {
      const float4 wv = Wq[k][j];        // one b128, 4 gate weights
      #pragma unroll
      for (int bb = 0; bb < NW; ++bb) {
        const float hv = readlane_f(h_reg[bb], k);   // SGPR broadcast, no LDS
        acc[bb][0] = fmaf(hv, wv.x, acc[bb][0]);
        acc[bb][1] = fmaf(hv, wv.y, acc[bb][1]);
        acc[bb][2] = fmaf(hv, wv.z, acc[bb][2]);
        acc[bb][3] = fmaf(hv, wv.w, acc[bb][3]);
      }
    }

    // ---- elementwise LSTM cell (all in registers) ----
    #pragma unroll
    for (int bb = 0; bb < NW; ++bb) {
      float gi = acc[bb][0] + biasr[0] + x0[bb] * wi0[0] + x1[bb] * wi1[0];
      float gf = acc[bb][1] + biasr[1] + x0[bb] * wi0[1] + x1[bb] * wi1[1];
      float gg = acc[bb][2] + biasr[2] + x0[bb] * wi0[2] + x1[bb] * wi1[2];
      float go = acc[bb][3] + biasr[3] + x0[bb] * wi0[3] + x1[bb] * wi1[3];
      float si = sigmoidf(gi);
      float sf = sigmoidf(gf);
      float tg = tanh_fast(gg);
      float so = sigmoidf(go);
      float cn = fmaf(sf, c[bb], si * tg);
      c[bb] = cn;
      h_reg[bb] = so * tanh_fast(cn);
    }

    // ---- decoder head: dxy = h @ W_dec.T + b_dec (wave-internal) ----
    if (s >= TSTEPS) {
      #pragma unroll
      for (int bb = 0; bb < NW; ++bb)
        hbuf[lb + bb][j] = h_reg[bb];    // wave-local, in-order

      const int bl = j >> 3;        // batch within wave (0..7)
      const int f  = (j >> 2) & 1;  // output feature
      const int p  = j & 3;         // k-slice
      const float* hr = &hbuf[lb + bl][p * 16];
      const float* wr = &Wd[f][p * 16];
      float part = 0.f;
      #pragma unroll
      for (int e = 0; e < 4; ++e) {
        float4 hv = *(const float4*)&hr[e * 4];
        float4 wv = *(const float4*)&wr[e * 4];
        part += hv.x * wv.x + hv.y * wv.y + hv.z * wv.z + hv.w * wv.w;
      }
      part += __shfl_xor(part, 1);
      part += __shfl_xor(part, 2);
      const float dxy = part + (f ? bd1 : bd0);
      if (p == 0) {
        xdec[lb + bl][f] = dxy;     // feedback for next step (same wave)
        out[(size_t)(gb + bl) * (HOR * 2) + (size_t)(s - TSTEPS) * 2 + f] = dxy;
      }
    }
  }
}

extern "C" void kernel_launch(void* const* d_in, const int* in_sizes, int n_in,
                              void* d_out, int out_size, void* d_ws, size_t ws_size,
                              hipStream_t stream) {
  (void)in_sizes; (void)n_in; (void)ws_size; (void)d_ws; (void)out_size;
  const float* hist  = (const float*)d_in[0];
  const float* W_ih  = (const float*)d_in[1];
  const float* W_hh  = (const float*)d_in[2];
  const float* b_ih  = (const float*)d_in[3];
  const float* b_hh  = (const float*)d_in[4];
  const float* W_dec = (const float*)d_in[5];
  const float* b_dec = (const float*)d_in[6];
  float* out = (float*)d_out;

  dim3 grid(NBATCH / NB);   // 512 blocks
  dim3 block(NTHREADS);
  traj_lstm_kernel<<<grid, block, 0, stream>>>(hist, W_ih, W_hh, b_ih, b_hh,
                                               W_dec, b_dec, out);
}

// Round 4
// 419.813 us; speedup vs baseline: 2.9025x; 2.9025x over previous
//
#include <hip/hip_runtime.h>

typedef __attribute__((ext_vector_type(8))) short short8;
typedef __attribute__((ext_vector_type(4))) float f32x4;
typedef __attribute__((ext_vector_type(2))) float f32x2;

#define TSTEPS 50
#define HOR    50

__device__ __forceinline__ float frcp(float x) { return __builtin_amdgcn_rcpf(x); }
__device__ __forceinline__ float sigmoidf(float x) { return frcp(1.f + __expf(-x)); }
__device__ __forceinline__ float tanh_fast(float x) {
  float ax = fabsf(x);
  float e  = __expf(-2.f * ax);
  float r  = (1.f - e) * frcp(1.f + e);
  return copysignf(r, x);
}
// fp32 -> bf16 (RNE) and back
__device__ __forceinline__ unsigned short f2bf(float f) {
  unsigned u = __float_as_uint(f);
  u += 0x7FFFu + ((u >> 16) & 1u);
  return (unsigned short)(u >> 16);
}
__device__ __forceinline__ float bf2f(unsigned short b) {
  return __uint_as_float(((unsigned)b) << 16);
}

__global__ __launch_bounds__(256, 1)
void traj_lstm_mfma(const float* __restrict__ hist,   // (B, 50, 2)
                    const float* __restrict__ W_ih,   // (256, 2)
                    const float* __restrict__ W_hh,   // (256, 64)
                    const float* __restrict__ b_ih,   // (256)
                    const float* __restrict__ b_hh,   // (256)
                    const float* __restrict__ W_dec,  // (2, 64)
                    const float* __restrict__ b_dec,  // (2)
                    float* __restrict__ out)          // (B, 50, 2)
{
  // per-wave h exchange: hsh[wave][batch m][hidden j], rows padded to 68
  __shared__ float hsh[4][16][68];

  const int tid  = threadIdx.x;
  const int w    = tid >> 6;
  const int lane = tid & 63;
  const int col  = lane & 15;   // MFMA col / A-row index
  const int g    = lane >> 4;   // lane group 0..3
  const int batch0 = blockIdx.x * 64 + w * 16;  // lane's batches: batch0 + 4g + r

  // ---- W_hh as persistent B-fragments (hi/lo bf16) in VGPRs ----
  // B[k][n]: n = 16t + col, k = 32q + 8g + e  (gates = h @ W_hh^T)
  short8 wbhi[16][2], wblo[16][2];
  #pragma unroll
  for (int t = 0; t < 16; ++t) {
    #pragma unroll
    for (int q = 0; q < 2; ++q) {
      const float* wr = &W_hh[(t * 16 + col) * 64 + q * 32 + g * 8];
      #pragma unroll
      for (int e = 0; e < 8; ++e) {
        float f = wr[e];
        unsigned short hb = f2bf(f);
        wbhi[t][q][e] = (short)hb;
        wblo[t][q][e] = (short)f2bf(f - bf2f(hb));
      }
    }
  }

  // ---- per-lane elementwise constants ----
  // cell (r, tj): hidden j = 16*tj + col, gate row = gt*64 + j
  float bias[4][4], wih0[4][4], wih1[4][4];
  #pragma unroll
  for (int gt = 0; gt < 4; ++gt) {
    #pragma unroll
    for (int tj = 0; tj < 4; ++tj) {
      int row = gt * 64 + tj * 16 + col;
      bias[gt][tj] = b_ih[row] + b_hh[row];
      wih0[gt][tj] = W_ih[row * 2];
      wih1[gt][tj] = W_ih[row * 2 + 1];
    }
  }
  float wd0[4], wd1[4];
  #pragma unroll
  for (int tj = 0; tj < 4; ++tj) {
    wd0[tj] = W_dec[tj * 16 + col];
    wd1[tj] = W_dec[64 + tj * 16 + col];
  }
  const float bd0 = b_dec[0], bd1 = b_dec[1];

  float cst[4][4];
  #pragma unroll
  for (int r = 0; r < 4; ++r)
    #pragma unroll
    for (int tj = 0; tj < 4; ++tj) {
      cst[r][tj] = 0.f;
      hsh[w][4 * g + r][tj * 16 + col] = 0.f;   // h0 = 0 (wave-local)
    }

  float fx0[4] = {0,0,0,0}, fx1[4] = {0,0,0,0};  // decode feedback

  for (int s = 0; s < TSTEPS + HOR; ++s) {
    // ---- x for this step (issue early; consumed after MFMAs) ----
    float x0[4], x1[4];
    if (s <= TSTEPS) {
      const int ss = (s < TSTEPS) ? s : (TSTEPS - 1);
      #pragma unroll
      for (int r = 0; r < 4; ++r) {
        f32x2 xv = *(const f32x2*)&hist[(size_t)(batch0 + 4 * g + r) * 100 + ss * 2];
        x0[r] = xv.x; x1[r] = xv.y;
      }
    } else {
      #pragma unroll
      for (int r = 0; r < 4; ++r) { x0[r] = fx0[r]; x1[r] = fx1[r]; }
    }

    // ---- A-fragments from hsh: A[m][k], m = col, k = 32q + 8g + e ----
    short8 ahi[2], alo[2];
    #pragma unroll
    for (int q = 0; q < 2; ++q) {
      f32x4 h0 = *(const f32x4*)&hsh[w][col][q * 32 + g * 8];
      f32x4 h1 = *(const f32x4*)&hsh[w][col][q * 32 + g * 8 + 4];
      #pragma unroll
      for (int e = 0; e < 8; ++e) {
        float f = (e < 4) ? h0[e] : h1[e - 4];
        unsigned short hb = f2bf(f);
        ahi[q][e] = (short)hb;
        alo[q][e] = (short)f2bf(f - bf2f(hb));
      }
    }

    // ---- gates = h @ W_hh^T via MFMA, 3-term bf16 split ----
    f32x4 acc[16];
    #pragma unroll
    for (int t = 0; t < 16; ++t) {
      f32x4 a = {0.f, 0.f, 0.f, 0.f};
      a = __builtin_amdgcn_mfma_f32_16x16x32_bf16(ahi[0], wbhi[t][0], a, 0, 0, 0);
      a = __builtin_amdgcn_mfma_f32_16x16x32_bf16(ahi[1], wbhi[t][1], a, 0, 0, 0);
      a = __builtin_amdgcn_mfma_f32_16x16x32_bf16(alo[0], wbhi[t][0], a, 0, 0, 0);
      a = __builtin_amdgcn_mfma_f32_16x16x32_bf16(alo[1], wbhi[t][1], a, 0, 0, 0);
      a = __builtin_amdgcn_mfma_f32_16x16x32_bf16(ahi[0], wblo[t][0], a, 0, 0, 0);
      a = __builtin_amdgcn_mfma_f32_16x16x32_bf16(ahi[1], wblo[t][1], a, 0, 0, 0);
      acc[t] = a;
    }

    // ---- LSTM cell, fully in-lane ----
    // D: row = 4g + r (batch), col = gate n = 16t + col; tiles 0-3=i,4-7=f,8-11=g,12-15=o
    float hnew[4][4];
    #pragma unroll
    for (int r = 0; r < 4; ++r) {
      #pragma unroll
      for (int tj = 0; tj < 4; ++tj) {
        float gi = acc[tj][r]      + bias[0][tj] + x0[r] * wih0[0][tj] + x1[r] * wih1[0][tj];
        float gf = acc[tj + 4][r]  + bias[1][tj] + x0[r] * wih0[1][tj] + x1[r] * wih1[1][tj];
        float gg = acc[tj + 8][r]  + bias[2][tj] + x0[r] * wih0[2][tj] + x1[r] * wih1[2][tj];
        float go = acc[tj + 12][r] + bias[3][tj] + x0[r] * wih0[3][tj] + x1[r] * wih1[3][tj];
        float si = sigmoidf(gi);
        float sf = sigmoidf(gf);
        float tg = tanh_fast(gg);
        float so = sigmoidf(go);
        float cn = fmaf(sf, cst[r][tj], si * tg);
        cst[r][tj] = cn;
        float hv = so * tanh_fast(cn);
        hnew[r][tj] = hv;
        hsh[w][4 * g + r][tj * 16 + col] = hv;   // wave-local, read next step
      }
    }

    // ---- decoder head (in-register, 16-lane butterfly) ----
    if (s >= TSTEPS) {
      float p0[4], p1[4];
      #pragma unroll
      for (int r = 0; r < 4; ++r) {
        p0[r] = hnew[r][0] * wd0[0] + hnew[r][1] * wd0[1] + hnew[r][2] * wd0[2] + hnew[r][3] * wd0[3];
        p1[r] = hnew[r][0] * wd1[0] + hnew[r][1] * wd1[1] + hnew[r][2] * wd1[2] + hnew[r][3] * wd1[3];
      }
      #pragma unroll
      for (int d = 1; d < 16; d <<= 1) {
        #pragma unroll
        for (int r = 0; r < 4; ++r) {
          p0[r] += __shfl_xor(p0[r], d);
          p1[r] += __shfl_xor(p1[r], d);
        }
      }
      #pragma unroll
      for (int r = 0; r < 4; ++r) {
        fx0[r] = p0[r] + bd0;   // feedback x for next step
        fx1[r] = p1[r] + bd1;
      }
      if (col == 0) {
        #pragma unroll
        for (int r = 0; r < 4; ++r) {
          f32x2 o2 = { fx0[r], fx1[r] };
          *(f32x2*)&out[(size_t)(batch0 + 4 * g + r) * 100 + (size_t)(s - TSTEPS) * 2] = o2;
        }
      }
    }
  }
}

extern "C" void kernel_launch(void* const* d_in, const int* in_sizes, int n_in,
                              void* d_out, int out_size, void* d_ws, size_t ws_size,
                              hipStream_t stream) {
  (void)in_sizes; (void)n_in; (void)ws_size; (void)d_ws; (void)out_size;
  const float* hist  = (const float*)d_in[0];
  const float* W_ih  = (const float*)d_in[1];
  const float* W_hh  = (const float*)d_in[2];
  const float* b_ih  = (const float*)d_in[3];
  const float* b_hh  = (const float*)d_in[4];
  const float* W_dec = (const float*)d_in[5];
  const float* b_dec = (const float*)d_in[6];
  float* out = (float*)d_out;

  dim3 grid(16384 / 64);   // 256 blocks, 4 waves each, 16 batches/wave
  dim3 block(256);
  traj_lstm_mfma<<<grid, block, 0, stream>>>(hist, W_ih, W_hh, b_ih, b_hh,
                                             W_dec, b_dec, out);
}

// Round 5
// 325.698 us; speedup vs baseline: 3.7413x; 1.2890x over previous
//
#include <hip/hip_runtime.h>

typedef __attribute__((ext_vector_type(8))) short short8;
typedef __attribute__((ext_vector_type(4))) float f32x4;
typedef __attribute__((ext_vector_type(2))) float f32x2;

#define TSTEPS 50
#define HOR    50

__device__ __forceinline__ float frcp(float x) { return __builtin_amdgcn_rcpf(x); }
__device__ __forceinline__ float sigmoidf(float x) { return frcp(1.f + __expf(-x)); }
__device__ __forceinline__ float tanh_fast(float x) {
  float ax = fabsf(x);
  float e  = __expf(-2.f * ax);
  float r  = (1.f - e) * frcp(1.f + e);
  return copysignf(r, x);
}
// packed f32->bf16 (RNE via hardware cvt); no builtin exists on gfx950 -> asm
__device__ __forceinline__ unsigned cvt_pk_bf16(float a, float b) {
  unsigned r;
  asm("v_cvt_pk_bf16_f32 %0, %1, %2" : "=v"(r) : "v"(a), "v"(b));
  return r;
}
union S8U { short8 s; unsigned u[4]; };

// 8 floats -> bf16 hi fragment + exact-residual lo fragment (Dekker split)
__device__ __forceinline__ void split8(const float* f, short8& hi, short8& lo) {
  S8U h, l;
  #pragma unroll
  for (int e = 0; e < 4; ++e) {
    float a = f[2 * e], b = f[2 * e + 1];
    unsigned ph = cvt_pk_bf16(a, b);
    float ah = __uint_as_float(ph << 16);          // bf2f(low short)
    float bh = __uint_as_float(ph & 0xFFFF0000u);  // bf2f(high short)
    h.u[e] = ph;
    l.u[e] = cvt_pk_bf16(a - ah, b - bh);          // residuals exact in fp32
  }
  hi = h.s; lo = l.s;
}

__global__ __launch_bounds__(256, 2)
void traj_lstm_mfma2(const float* __restrict__ hist,   // (B, 50, 2)
                     const float* __restrict__ W_ih,   // (256, 2)
                     const float* __restrict__ W_hh,   // (256, 64)
                     const float* __restrict__ b_ih,   // (256)
                     const float* __restrict__ b_hh,   // (256)
                     const float* __restrict__ W_dec,  // (2, 64)
                     const float* __restrict__ b_dec,  // (2)
                     float* __restrict__ out)          // (B, 50, 2)
{
  // double-buffered h exchange per wave-pair: [buf][pair][batch][hidden j]
  __shared__ float hsh[2][2][16][68];
  __shared__ float xsh[2][16][2];   // decode feedback [pair][batch][feat]
  __shared__ float wdl[2][64];      // W_dec rows

  const int tid  = threadIdx.x;
  const int w    = tid >> 6;
  const int lane = tid & 63;
  const int col  = lane & 15;   // MFMA col / batch row of A
  const int g    = lane >> 4;   // lane group 0..3
  const int pr   = w >> 1;      // pair (16-batch group) 0/1
  const int p    = w & 1;       // gate-split half: hidden j in [32p, 32p+32)
  const int batch0 = blockIdx.x * 32 + pr * 16;

  // ---- W_hh fragments for this wave's 8 tiles (hi/lo bf16), persistent ----
  // tile (gt,u): gate gt, hidden col-tile tj = 2p+u. B[k][n]: n=col, k=32q+8g+e
  short8 wbhi[4][2][2], wblo[4][2][2];
  #pragma unroll
  for (int gt = 0; gt < 4; ++gt)
    #pragma unroll
    for (int u = 0; u < 2; ++u) {
      const int row = gt * 64 + (2 * p + u) * 16 + col;
      #pragma unroll
      for (int q = 0; q < 2; ++q) {
        float f[8];
        #pragma unroll
        for (int e = 0; e < 8; ++e) f[e] = W_hh[row * 64 + q * 32 + g * 8 + e];
        split8(f, wbhi[gt][u][q], wblo[gt][u][q]);
      }
    }

  // ---- per-cell constants (8 cells/lane: 4 batches x 2 hidden tiles) ----
  float bias[4][2], wih0[4][2], wih1[4][2];
  #pragma unroll
  for (int gt = 0; gt < 4; ++gt)
    #pragma unroll
    for (int u = 0; u < 2; ++u) {
      const int row = gt * 64 + (2 * p + u) * 16 + col;
      bias[gt][u] = b_ih[row] + b_hh[row];
      wih0[gt][u] = W_ih[row * 2];
      wih1[gt][u] = W_ih[row * 2 + 1];
    }
  const float bdp = b_dec[p];

  if (tid < 128) wdl[tid >> 6][tid & 63] = W_dec[tid];
  for (int i = tid; i < 2 * 16 * 68; i += 256) ((float*)hsh[0])[i] = 0.f;  // h0=0

  float cst[4][2];
  #pragma unroll
  for (int r = 0; r < 4; ++r)
    #pragma unroll
    for (int u = 0; u < 2; ++u) cst[r][u] = 0.f;

  __syncthreads();

  for (int s = 0; s < TSTEPS + HOR; ++s) {
    const int par = s & 1;

    // ---- A fragments from hsh[par]: A[m=col][k=32q+8g+e], hi/lo ----
    short8 ahi[2], alo[2];
    #pragma unroll
    for (int q = 0; q < 2; ++q) {
      float hf[8];
      *(f32x4*)&hf[0] = *(const f32x4*)&hsh[par][pr][col][q * 32 + g * 8];
      *(f32x4*)&hf[4] = *(const f32x4*)&hsh[par][pr][col][q * 32 + g * 8 + 4];
      split8(hf, ahi[q], alo[q]);
    }

    // ---- x for this step (lane's batches: 4g+r) ----
    float x0[4], x1[4];
    if (s <= TSTEPS) {
      const int ss = (s < TSTEPS) ? s : (TSTEPS - 1);
      #pragma unroll
      for (int r = 0; r < 4; ++r) {
        f32x2 xv = *(const f32x2*)&hist[(size_t)(batch0 + 4 * g + r) * 100 + ss * 2];
        x0[r] = xv.x; x1[r] = xv.y;
      }
    } else {
      #pragma unroll
      for (int r = 0; r < 4; ++r) {
        f32x2 xv = *(const f32x2*)&xsh[pr][4 * g + r][0];
        x0[r] = xv.x; x1[r] = xv.y;
      }
    }

    // ---- 48 MFMAs: this wave's 8 gate-tiles, 3-term bf16 split ----
    f32x4 acc[4][2];
    #pragma unroll
    for (int gt = 0; gt < 4; ++gt)
      #pragma unroll
      for (int u = 0; u < 2; ++u) {
        f32x4 a = {0.f, 0.f, 0.f, 0.f};
        a = __builtin_amdgcn_mfma_f32_16x16x32_bf16(ahi[0], wbhi[gt][u][0], a, 0, 0, 0);
        a = __builtin_amdgcn_mfma_f32_16x16x32_bf16(ahi[1], wbhi[gt][u][1], a, 0, 0, 0);
        a = __builtin_amdgcn_mfma_f32_16x16x32_bf16(alo[0], wbhi[gt][u][0], a, 0, 0, 0);
        a = __builtin_amdgcn_mfma_f32_16x16x32_bf16(alo[1], wbhi[gt][u][1], a, 0, 0, 0);
        a = __builtin_amdgcn_mfma_f32_16x16x32_bf16(ahi[0], wblo[gt][u][0], a, 0, 0, 0);
        a = __builtin_amdgcn_mfma_f32_16x16x32_bf16(ahi[1], wblo[gt][u][1], a, 0, 0, 0);
        acc[gt][u] = a;
      }

    // ---- LSTM cell: D row = 4g+r (batch), col = this wave's hidden j ----
    #pragma unroll
    for (int r = 0; r < 4; ++r)
      #pragma unroll
      for (int u = 0; u < 2; ++u) {
        float gi = acc[0][u][r] + bias[0][u] + x0[r] * wih0[0][u] + x1[r] * wih1[0][u];
        float gf = acc[1][u][r] + bias[1][u] + x0[r] * wih0[1][u] + x1[r] * wih1[1][u];
        float gg = acc[2][u][r] + bias[2][u] + x0[r] * wih0[2][u] + x1[r] * wih1[2][u];
        float go = acc[3][u][r] + bias[3][u] + x0[r] * wih0[3][u] + x1[r] * wih1[3][u];
        float si = sigmoidf(gi);
        float sf = sigmoidf(gf);
        float tg = tanh_fast(gg);
        float so = sigmoidf(go);
        float cn = fmaf(sf, cst[r][u], si * tg);
        cst[r][u] = cn;
        float hv = so * tanh_fast(cn);
        hsh[par ^ 1][pr][4 * g + r][(2 * p + u) * 16 + col] = hv;
      }
    __syncthreads();   // h[s+1] visible to pair partner (and decoder)

    // ---- decoder head: wave p computes feature p for its pair's 16 batches ----
    if (s >= TSTEPS) {
      const float* hr = &hsh[par ^ 1][pr][col][g * 16];  // batch=col, slice=g
      const float* wr = &wdl[p][g * 16];
      float part = 0.f;
      #pragma unroll
      for (int e4 = 0; e4 < 4; ++e4) {
        f32x4 hv = *(const f32x4*)&hr[e4 * 4];
        f32x4 wv = *(const f32x4*)&wr[e4 * 4];
        part += hv.x * wv.x + hv.y * wv.y + hv.z * wv.z + hv.w * wv.w;
      }
      part += __shfl_xor(part, 16);
      part += __shfl_xor(part, 32);
      const float dxy = part + bdp;
      if (g == 0) {
        xsh[pr][col][p] = dxy;   // feedback x for step s+1
        out[(size_t)(batch0 + col) * 100 + (size_t)(s - TSTEPS) * 2 + p] = dxy;
      }
      __syncthreads();  // xsh visible before next step's reads
    }
  }
}

extern "C" void kernel_launch(void* const* d_in, const int* in_sizes, int n_in,
                              void* d_out, int out_size, void* d_ws, size_t ws_size,
                              hipStream_t stream) {
  (void)in_sizes; (void)n_in; (void)ws_size; (void)d_ws; (void)out_size;
  const float* hist  = (const float*)d_in[0];
  const float* W_ih  = (const float*)d_in[1];
  const float* W_hh  = (const float*)d_in[2];
  const float* b_ih  = (const float*)d_in[3];
  const float* b_hh  = (const float*)d_in[4];
  const float* W_dec = (const float*)d_in[5];
  const float* b_dec = (const float*)d_in[6];
  float* out = (float*)d_out;

  dim3 grid(16384 / 32);   // 512 blocks x 4 waves: 2 pairs x 2 gate-split waves
  dim3 block(256);
  traj_lstm_mfma2<<<grid, block, 0, stream>>>(hist, W_ih, W_hh, b_ih, b_hh,
                                              W_dec, b_dec, out);
}